// Round 5
// baseline (329.815 us; speedup 1.0000x reference)
//
#include <hip/hip_runtime.h>
#include <cstdint>
#include <cstddef>

#define B_DIM 512
#define T_DIM 200
#define D_DIM 512
#define NPAD  208   // N padded to 13*16
#define NKG   28    // K padded to 224 = 28 groups of 8
#define NT    13    // n-tiles of 16
#define KS_STEPS 7  // 224 / 32
#define NFRAG 91    // 7 ks * 13 nt
#define PIPE  8     // B-frag pipeline depth (32 VGPRs)
// LDS slice per wave: only kg 0..24 stored (t=0..199); kg 25..27 are always
// zero -> exec-masked a=0. 25*16*8 = 3200 shorts + 8 pad shorts.
#define SLICE 3208

typedef short  short8  __attribute__((ext_vector_type(8)));
typedef float  floatx4 __attribute__((ext_vector_type(4)));

__device__ __forceinline__ unsigned short f2bf(float f) {
  unsigned int u = __float_as_uint(f);
  u += 0x7fffu + ((u >> 16) & 1u);   // round-to-nearest-even
  return (unsigned short)(u >> 16);
}
__device__ __forceinline__ float bf2f(unsigned short h) {
  return __uint_as_float(((unsigned int)h) << 16);
}
// packed f32x2 -> bf16x2 (RTNE), lo = a, hi = b. Non-volatile: schedulable.
__device__ __forceinline__ unsigned int cvt_pk_bf16(float a, float b) {
  unsigned int d;
  asm("v_cvt_pk_bf16_f32 %0, %1, %2" : "=v"(d) : "v"(a), "v"(b));
  return d;
}

// W (200x200 fp32) -> bf16, padded 224x208, B-fragment layout [k/8][n][k%8]
__global__ void prep_w_kernel(const float* __restrict__ W,
                              unsigned short* __restrict__ wf) {
  int idx = blockIdx.x * blockDim.x + threadIdx.x;
  if (idx >= NKG * 8 * NPAD) return;
  int k = idx / NPAD;
  int n = idx - k * NPAD;
  float v = (k < T_DIM && n < T_DIM) ? W[k * T_DIM + n] : 0.0f;
  wf[((size_t)(k >> 3) * NPAD + n) * 8 + (k & 7)] = f2bf(v);
}

// R3 post-mortem: acc[13] lives in the unified AGPR half (52 regs) ->
// total was ~116/128 already; b0[7]+b1[6] (52 regs) overflowed -> 12 MB
// scratch spill. R4: flat modulo-8 pipeline (buf[8] = 32 regs, all static
// indices), 7-8 loads continuously in flight, total ~112 <= 128. No spill.
__global__ __launch_bounds__(256, 4)
void attn_kernel(const float* __restrict__ X,
                 const unsigned short* __restrict__ wf,
                 const float* __restrict__ bias,
                 float* __restrict__ out) {
  __shared__ __align__(16) unsigned short Xa[4 * SLICE];

  const int tid  = threadIdx.x;
  const int wv   = tid >> 6;
  const int lane = tid & 63;
  const int l15  = lane & 15;
  const int g    = lane >> 4;

  const int bid  = blockIdx.x;
  const int bb   = bid >> 3;              // batch item (8 blocks per item)
  const int dblk = (bid & 7) << 6;        // block's 64-col origin
  const int d0   = dblk + (wv << 4);      // this wave's 16-col tile

  // ---- cooperative staging: i = t*16 + c4 covers 200 rows x 16 float4.
  // Consecutive tids cover one 256 B row-slice -> perfectly coalesced.
  {
    const float* xb = X + (size_t)bb * (T_DIM * D_DIM) + dblk;
    #pragma unroll
    for (int it = 0; it < 13; ++it) {
      int i = it * 256 + tid;
      if (it < 12 || tid < 128) {        // 12 full rounds + 128-thread tail
        int t  = i >> 4;
        int c4 = i & 15;
        float4 v = *(const float4*)(xb + (size_t)t * D_DIM + (c4 << 2));
        unsigned short* dst = Xa + (c4 >> 2) * SLICE
                            + ((t >> 3) * 16 + ((c4 & 3) << 2)) * 8 + (t & 7);
        unsigned int w01 = cvt_pk_bf16(v.x, v.y);
        unsigned int w23 = cvt_pk_bf16(v.z, v.w);
        dst[0]  = (unsigned short)(w01 & 0xffffu);
        dst[8]  = (unsigned short)(w01 >> 16);
        dst[16] = (unsigned short)(w23 & 0xffffu);
        dst[24] = (unsigned short)(w23 >> 16);
      }
    }
  }
  __syncthreads();

  unsigned short* Xw = Xa + wv * SLICE;
  const unsigned short* wl = wf + (size_t)l15 * 8;   // lane base into wf

  floatx4 acc[NT];
  #pragma unroll
  for (int nt = 0; nt < NT; ++nt)
    acc[nt] = (floatx4){0.f, 0.f, 0.f, 0.f};

  // frag f (compile-time after unroll): ks = f/13, nt = f%13, kg = ks*4+g
#define BLOADF(dst, f) do {                                                  \
    const int _ks = (f) / NT, _nt = (f) % NT;                                \
    (dst) = *(const short8*)(wl + ((size_t)(_ks * 4 + g) * NPAD + _nt * 16) * 8); \
  } while (0)

  // ---- K-loop: flat software pipeline, depth 8, no barriers.
  short8 buf[PIPE];
  short8 a_cur, a_nxt;

  a_cur = *(const short8*)&Xw[((g * 16) + l15) * 8];   // ks=0 A-frag
  #pragma unroll
  for (int f = 0; f < PIPE; ++f) BLOADF(buf[f], f);

  #pragma unroll
  for (int f = 0; f < NFRAG; ++f) {
    const int nt   = f % NT;
    const int ks   = f / NT;
    const int slot = f % PIPE;
    acc[nt] = __builtin_amdgcn_mfma_f32_16x16x32_bf16(a_cur, buf[slot], acc[nt], 0, 0, 0);
    if (f + PIPE < NFRAG) BLOADF(buf[slot], f + PIPE);  // refill after consume
    if (nt == 6 && ks < 6) {
      // prefetch next ks A-frag mid-tile; kg 25..27 (t>=200) are zero.
      const int kgn = (ks + 1) * 4 + g;
      if (ks < 5 || g == 0)
        a_nxt = *(const short8*)&Xw[((kgn * 16) + l15) * 8];
      else
        a_nxt = (short8){0, 0, 0, 0, 0, 0, 0, 0};
    }
    if (nt == NT - 1) a_cur = a_nxt;
  }
#undef BLOADF

  // ---- fused epilogue: p = exp(tanh(z)); tanh bounded => no max pass.
  // C/D layout: col = lane&15 (= t within tile), row m = g*4 + r.
  // nt 0..11: t = nt*16+l15 <= 191 < 200, provably valid -> no predication.
  float part[4] = {0.f, 0.f, 0.f, 0.f};
  float rs[4]   = {0.f, 0.f, 0.f, 0.f};
  #pragma unroll
  for (int nt = 0; nt < 12; ++nt) {
    const int t = nt * 16 + l15;
    const float bvn = bias[t];
    const unsigned short* xp = &Xw[((t >> 3) * 16) * 8 + (t & 7)];
    #pragma unroll
    for (int r = 0; r < 4; ++r) {
      float z  = acc[nt][r] + bvn;
      float e  = __expf(2.0f * z);              // tanh = 1 - 2/(e^{2z}+1)
      float th = 1.0f - __fdividef(2.0f, e + 1.0f);
      float p  = __expf(th);
      rs[r]   += p;
      part[r] += p * bf2f(xp[(g * 4 + r) * 8]); // X[t][d0+m]
    }
  }
  { // tail nt=12: t = 192+l15, valid iff l15 < 8
    const bool valid = (l15 < 8);
    const int tc = valid ? (192 + l15) : 199;
    const float bvn = bias[tc];
    const unsigned short* xp = &Xw[((tc >> 3) * 16) * 8 + (tc & 7)];
    #pragma unroll
    for (int r = 0; r < 4; ++r) {
      float z  = acc[12][r] + bvn;
      float e  = __expf(2.0f * z);
      float th = 1.0f - __fdividef(2.0f, e + 1.0f);
      float p  = valid ? __expf(th) : 0.0f;
      rs[r]   += p;
      part[r] += p * bf2f(xp[(g * 4 + r) * 8]);
    }
  }
  // reduce over the 16 t-lanes (each (g,r) is a distinct output row)
  #pragma unroll
  for (int off = 1; off <= 8; off <<= 1)
    #pragma unroll
    for (int r = 0; r < 4; ++r) {
      part[r] += __shfl_xor(part[r], off, 16);
      rs[r]   += __shfl_xor(rs[r],   off, 16);
    }

  if (l15 == 0) {
    #pragma unroll
    for (int r = 0; r < 4; ++r)
      out[(size_t)bb * D_DIM + d0 + g * 4 + r] = part[r] * __frcp_rn(rs[r]);
  }
}

extern "C" void kernel_launch(void* const* d_in, const int* in_sizes, int n_in,
                              void* d_out, int out_size, void* d_ws, size_t ws_size,
                              hipStream_t stream) {
  const float* X  = (const float*)d_in[0];
  const float* W  = (const float*)d_in[1];
  const float* bs = (const float*)d_in[2];
  float* out = (float*)d_out;
  unsigned short* wf = (unsigned short*)d_ws;  // needs 224*208*2 = 93,184 B

  const int wtot = NKG * 8 * NPAD;
  hipLaunchKernelGGL(prep_w_kernel, dim3((wtot + 255) / 256), dim3(256), 0, stream,
                     W, wf);
  // 16384 waves = 512 b * 32 d-tiles; 4 cooperative waves per block
  hipLaunchKernelGGL(attn_kernel, dim3(4096), dim3(256), 0, stream,
                     X, wf, bs, out);
}

// Round 6
// 319.584 us; speedup vs baseline: 1.0320x; 1.0320x over previous
//
#include <hip/hip_runtime.h>
#include <cstdint>
#include <cstddef>

#define B_DIM 512
#define T_DIM 200
#define D_DIM 512
#define NPAD  208   // N padded to 13*16
#define NKG   28    // K padded to 224 = 28 groups of 8
#define NT    13    // n-tiles of 16
#define KS_STEPS 7  // 224 / 32
// One 16-col X slice in LDS: [kg 0..24][m 0..15][j 0..7] bf16 = 3200 shorts
// + 8 pad shorts. Two slices per block (32 d-cols) = 12,832 B + 1 KB combine.
#define SLICE 3208

typedef short  short8  __attribute__((ext_vector_type(8)));
typedef float  floatx4 __attribute__((ext_vector_type(4)));

__device__ __forceinline__ unsigned short f2bf(float f) {
  unsigned int u = __float_as_uint(f);
  u += 0x7fffu + ((u >> 16) & 1u);   // round-to-nearest-even
  return (unsigned short)(u >> 16);
}
__device__ __forceinline__ float bf2f(unsigned short h) {
  return __uint_as_float(((unsigned int)h) << 16);
}
// packed f32x2 -> bf16x2 (RTNE)
__device__ __forceinline__ unsigned int cvt_pk_bf16(float a, float b) {
  unsigned int d;
  asm("v_cvt_pk_bf16_f32 %0, %1, %2" : "=v"(d) : "v"(a), "v"(b));
  return d;
}

// W (200x200 fp32) -> bf16, padded 224x208, B-fragment layout [k/8][n][k%8]
__global__ void prep_w_kernel(const float* __restrict__ W,
                              unsigned short* __restrict__ wf) {
  int idx = blockIdx.x * blockDim.x + threadIdx.x;
  if (idx >= NKG * 8 * NPAD) return;
  int k = idx / NPAD;
  int n = idx - k * NPAD;
  float v = (k < T_DIM && n < T_DIM) ? W[k * T_DIM + n] : 0.0f;
  wf[((size_t)(k >> 3) * NPAD + n) * 8 + (k & 7)] = f2bf(v);
}

// R5 post-mortem: one-wave-owns-full-s-row => acc[13]=52 AGPR => 128 total
// regs/wave => HARD cap 4 waves/SIMD; each wave streams all 93 KB of wf
// (no L1 reuse, 1.5 GB L2). Restructure: block = 4 waves sharing a 32-col
// d-tile; s-axis SPLIT across waves (tiles 4/3/3/3; softmax num & denom are
// plain sums over s -> partials combine in LDS). Each B-frag feeds 2 MFMAs
// (wf L2 traffic halves), acc = 32 AGPR, per-wave L1 working set ~23-28 KB
// fits L1, reg demand ~96-104 -> 4-5 waves/SIMD.
__global__ __launch_bounds__(256, 4)
void attn_kernel(const float* __restrict__ X,
                 const unsigned short* __restrict__ wf,
                 const float* __restrict__ bias,
                 float* __restrict__ out) {
  __shared__ __align__(16) unsigned short Xs[2 * SLICE];
  __shared__ __align__(16) float comb[4][32][2];   // [wave][row][part,rs]

  const int tid  = threadIdx.x;
  const int wv   = tid >> 6;
  const int lane = tid & 63;
  const int l15  = lane & 15;
  const int g    = lane >> 4;

  const int bid  = blockIdx.x;
  const int bb   = bid >> 4;              // batch item (16 blocks per item)
  const int dblk = (bid & 15) << 5;       // block's 32-col origin

  // ---- cooperative staging: 200 rows x 8 float4 (32 cols) = 1600 float4.
  // Consecutive tids cover 128 B row segments -> coalesced.
  {
    const float* xb = X + (size_t)bb * (T_DIM * D_DIM) + dblk;
    #pragma unroll
    for (int it = 0; it < 7; ++it) {
      int i = it * 256 + tid;
      if (it < 6 || tid < 64) {           // 6*256 + 64 = 1600
        int t  = i >> 3;
        int c4 = i & 7;                   // float4 index within row
        float4 v = *(const float4*)(xb + (size_t)t * D_DIM + (c4 << 2));
        // slice h = c4>>2 (cols h*16+..), col-within-slice = (c4&3)*4 + e
        unsigned short* dst = Xs + (c4 >> 2) * SLICE
                            + ((t >> 3) * 16 + ((c4 & 3) << 2)) * 8 + (t & 7);
        unsigned int w01 = cvt_pk_bf16(v.x, v.y);
        unsigned int w23 = cvt_pk_bf16(v.z, v.w);
        dst[0]  = (unsigned short)(w01 & 0xffffu);
        dst[8]  = (unsigned short)(w01 >> 16);
        dst[16] = (unsigned short)(w23 & 0xffffu);
        dst[24] = (unsigned short)(w23 >> 16);
      }
    }
  }
  __syncthreads();

  // wave's s-range: wave0 -> nt 0..3, wave w>=1 -> nt 1+3w .. 3+3w
  const int nt0 = (wv == 0) ? 0 : (1 + 3 * wv);   // 0,4,7,10
  const int ntw = (wv == 0) ? 4 : 3;

  floatx4 acc[2][4];
  #pragma unroll
  for (int h = 0; h < 2; ++h)
    #pragma unroll
    for (int j = 0; j < 4; ++j)
      acc[h][j] = (floatx4){0.f, 0.f, 0.f, 0.f};

  // per-lane base into wf for (kg = g, nt = nt0): frag j at +j*256 B,
  // ks step at +4*NPAD*8 shorts = 13,312 B (compile-time multiples).
  const unsigned short* wk = wf + ((size_t)g * NPAD + nt0 * 16 + l15) * 8;

  // ---- K-loop: per-ks double-buffered B-frags; one B-frag feeds BOTH
  // d-halves' MFMAs. A-frags from shared LDS slices.
  short8 bc[4], bn[4];
  short8 a0c, a1c, a0n, a1n;

  // prologue: ks=0 (kg = g <= 3, always valid)
  #pragma unroll
  for (int j = 0; j < 4; ++j)
    if (j < ntw) bc[j] = *(const short8*)(wk + j * 128);
  a0c = *(const short8*)&Xs[(g * 16 + l15) * 8];
  a1c = *(const short8*)&Xs[SLICE + (g * 16 + l15) * 8];

  #pragma unroll
  for (int ks = 0; ks < KS_STEPS; ++ks) {
    if (ks < 6) {
      const unsigned short* wkn = wk + (size_t)(ks + 1) * (4 * NPAD * 8);
      #pragma unroll
      for (int j = 0; j < 4; ++j)
        if (j < ntw) bn[j] = *(const short8*)(wkn + j * 128);
      const int kgn = (ks + 1) * 4 + g;
      if (ks < 5 || g == 0) {             // kg 25..27 (t>=200) are zero
        a0n = *(const short8*)&Xs[(kgn * 16 + l15) * 8];
        a1n = *(const short8*)&Xs[SLICE + (kgn * 16 + l15) * 8];
      } else {
        a0n = (short8){0, 0, 0, 0, 0, 0, 0, 0};
        a1n = (short8){0, 0, 0, 0, 0, 0, 0, 0};
      }
    }
    #pragma unroll
    for (int j = 0; j < 4; ++j)
      if (j < ntw) {
        acc[0][j] = __builtin_amdgcn_mfma_f32_16x16x32_bf16(a0c, bc[j], acc[0][j], 0, 0, 0);
        acc[1][j] = __builtin_amdgcn_mfma_f32_16x16x32_bf16(a1c, bc[j], acc[1][j], 0, 0, 0);
      }
    if (ks < 6) {
      a0c = a0n; a1c = a1n;
      #pragma unroll
      for (int j = 0; j < 4; ++j) bc[j] = bn[j];
    }
  }

  // ---- fused epilogue (partial over this wave's s-range):
  // p = exp(tanh(z)), tanh bounded => no max pass.
  // C/D layout: col = l15 (= s within tile), row m = g*4 + r.
  float part[2][4], rs[2][4];
  #pragma unroll
  for (int h = 0; h < 2; ++h)
    #pragma unroll
    for (int r = 0; r < 4; ++r) { part[h][r] = 0.f; rs[h][r] = 0.f; }

  #pragma unroll
  for (int j = 0; j < 4; ++j) {
    if (j < ntw) {
      const int nt = nt0 + j;
      const int t  = nt * 16 + l15;
      const bool valid = (t < T_DIM);     // only fails for nt==12, l15>=8
      const int tc = valid ? t : (T_DIM - 1);
      const float bvn = bias[tc];
      const unsigned short* xp = &Xs[((tc >> 3) * 16) * 8 + (tc & 7)];
      #pragma unroll
      for (int r = 0; r < 4; ++r) {
        const int m = g * 4 + r;
        #pragma unroll
        for (int h = 0; h < 2; ++h) {
          float z  = acc[h][j][r] + bvn;
          float e  = __expf(2.0f * z);            // tanh = 1 - 2/(e^{2z}+1)
          float th = 1.0f - __fdividef(2.0f, e + 1.0f);
          float p  = valid ? __expf(th) : 0.0f;
          rs[h][r]   += p;
          part[h][r] += p * bf2f(xp[h * SLICE + m * 8]);  // X[t][dblk+h*16+m]
        }
      }
    }
  }
  // reduce over the 16 s-lanes
  #pragma unroll
  for (int off = 1; off <= 8; off <<= 1)
    #pragma unroll
    for (int h = 0; h < 2; ++h)
      #pragma unroll
      for (int r = 0; r < 4; ++r) {
        part[h][r] += __shfl_xor(part[h][r], off, 16);
        rs[h][r]   += __shfl_xor(rs[h][r],   off, 16);
      }

  // ---- cross-wave combine of s-partials
  if (l15 == 0) {
    #pragma unroll
    for (int h = 0; h < 2; ++h)
      #pragma unroll
      for (int r = 0; r < 4; ++r) {
        comb[wv][h * 16 + g * 4 + r][0] = part[h][r];
        comb[wv][h * 16 + g * 4 + r][1] = rs[h][r];
      }
  }
  __syncthreads();

  if (tid < 32) {
    float ps = 0.f, ss = 0.f;
    #pragma unroll
    for (int w = 0; w < 4; ++w) {
      ps += comb[w][tid][0];
      ss += comb[w][tid][1];
    }
    out[(size_t)bb * D_DIM + dblk + tid] = ps * __frcp_rn(ss);
  }
}

extern "C" void kernel_launch(void* const* d_in, const int* in_sizes, int n_in,
                              void* d_out, int out_size, void* d_ws, size_t ws_size,
                              hipStream_t stream) {
  const float* X  = (const float*)d_in[0];
  const float* W  = (const float*)d_in[1];
  const float* bs = (const float*)d_in[2];
  float* out = (float*)d_out;
  unsigned short* wf = (unsigned short*)d_ws;  // needs 224*208*2 = 93,184 B

  const int wtot = NKG * 8 * NPAD;
  hipLaunchKernelGGL(prep_w_kernel, dim3((wtot + 255) / 256), dim3(256), 0, stream,
                     W, wf);
  // 8192 blocks = 512 b * 16 d-tiles(32 cols); 4 s-split waves per block
  hipLaunchKernelGGL(attn_kernel, dim3(8192), dim3(256), 0, stream,
                     X, wf, bs, out);
}

// Round 7
// 317.749 us; speedup vs baseline: 1.0380x; 1.0058x over previous
//
#include <hip/hip_runtime.h>
#include <cstdint>
#include <cstddef>

#define B_DIM 512
#define T_DIM 200
#define D_DIM 512
#define NPAD  208   // N padded to 13*16
#define NKG   28    // K padded to 224 = 28 groups of 8
#define NT    13    // n-tiles of 16
#define KS_STEPS 7  // 224 / 32
// One 16-col X slice in LDS: [kg 0..24][m 0..15][j 0..7] bf16 = 3200 shorts
// + 8 pad shorts (bank stagger). FOUR slices per block (64 d-cols).
#define SLICE 3208

typedef short  short8  __attribute__((ext_vector_type(8)));
typedef float  floatx4 __attribute__((ext_vector_type(4)));

__device__ __forceinline__ unsigned short f2bf(float f) {
  unsigned int u = __float_as_uint(f);
  u += 0x7fffu + ((u >> 16) & 1u);   // round-to-nearest-even
  return (unsigned short)(u >> 16);
}
__device__ __forceinline__ float bf2f(unsigned short h) {
  return __uint_as_float(((unsigned int)h) << 16);
}
// packed f32x2 -> bf16x2 (RTNE)
__device__ __forceinline__ unsigned int cvt_pk_bf16(float a, float b) {
  unsigned int d;
  asm("v_cvt_pk_bf16_f32 %0, %1, %2" : "=v"(d) : "v"(a), "v"(b));
  return d;
}

// W (200x200 fp32) -> bf16, padded 224x208, B-fragment layout [k/8][n][k%8]
__global__ void prep_w_kernel(const float* __restrict__ W,
                              unsigned short* __restrict__ wf) {
  int idx = blockIdx.x * blockDim.x + threadIdx.x;
  if (idx >= NKG * 8 * NPAD) return;
  int k = idx / NPAD;
  int n = idx - k * NPAD;
  float v = (k < T_DIM && n < T_DIM) ? W[k * T_DIM + n] : 0.0f;
  wf[((size_t)(k >> 3) * NPAD + n) * 8 + (k & 7)] = f2bf(v);
}

// R6 post-mortem: no pipe saturated; binding constraint is Little's law --
// ~128 B in flight/wave at ~250 cyc L2 latency caps delivered BW, and the
// dominant traffic is wf re-fetch (764 MB: each B-frag fed only 2 MFMAs).
// R7: widen block d-tile to 64 cols (4 slices). Each B-frag now feeds 4
// MFMAs -> wf L2 traffic halves (~380 MB), total L2 bytes ~0.68x. Regs:
// acc[4][4]=64 (AGPR) + B 16 + A 16 + ~20 addr ~= 116 <= 128 -> no
// software pipeline (single-buffered B/A), latency hiding left to TLP.
__global__ __launch_bounds__(256, 4)
void attn_kernel(const float* __restrict__ X,
                 const unsigned short* __restrict__ wf,
                 const float* __restrict__ bias,
                 float* __restrict__ out) {
  __shared__ __align__(16) unsigned short Xs[4 * SLICE];
  __shared__ __align__(16) float comb[4][64][2];   // [wave][d-col][part,rs]

  const int tid  = threadIdx.x;
  const int wv   = tid >> 6;
  const int lane = tid & 63;
  const int l15  = lane & 15;
  const int g    = lane >> 4;

  const int bid  = blockIdx.x;
  const int bb   = bid >> 3;              // batch item (8 blocks per item)
  const int dblk = (bid & 7) << 6;        // block's 64-col origin

  // ---- cooperative staging: 200 rows x 16 float4 (64 cols) = 3200 float4.
  // Consecutive tids cover 256 B row segments -> perfectly coalesced.
  {
    const float* xb = X + (size_t)bb * (T_DIM * D_DIM) + dblk;
    #pragma unroll
    for (int it = 0; it < 13; ++it) {
      int i = it * 256 + tid;
      if (it < 12 || tid < 128) {         // 12*256 + 128 = 3200
        int t  = i >> 4;
        int c4 = i & 15;                  // float4 index within 64-col row
        float4 v = *(const float4*)(xb + (size_t)t * D_DIM + (c4 << 2));
        // slice h = c4>>2 (cols h*16..), col-within-slice = (c4&3)*4 + e
        unsigned short* dst = Xs + (c4 >> 2) * SLICE
                            + ((t >> 3) * 16 + ((c4 & 3) << 2)) * 8 + (t & 7);
        unsigned int w01 = cvt_pk_bf16(v.x, v.y);
        unsigned int w23 = cvt_pk_bf16(v.z, v.w);
        dst[0]  = (unsigned short)(w01 & 0xffffu);
        dst[8]  = (unsigned short)(w01 >> 16);
        dst[16] = (unsigned short)(w23 & 0xffffu);
        dst[24] = (unsigned short)(w23 >> 16);
      }
    }
  }
  __syncthreads();

  // wave's s-range: wave0 -> nt 0..3, wave w>=1 -> nt 1+3w .. 3+3w
  const int nt0 = (wv == 0) ? 0 : (1 + 3 * wv);   // 0,4,7,10
  const int ntw = (wv == 0) ? 4 : 3;

  floatx4 acc[4][4];                      // [h = d-slice][j = s-tile]
  #pragma unroll
  for (int h = 0; h < 4; ++h)
    #pragma unroll
    for (int j = 0; j < 4; ++j)
      acc[h][j] = (floatx4){0.f, 0.f, 0.f, 0.f};

  // per-lane base into wf for (kg = g, nt = nt0): frag j at +j*256 B,
  // ks step at +4*NPAD*8 shorts (compile-time multiples).
  const unsigned short* wk = wf + ((size_t)g * NPAD + nt0 * 16 + l15) * 8;

  // ---- K-loop: one B-frag feeds FOUR d-slices' MFMAs. Single-buffered.
  #pragma unroll
  for (int ks = 0; ks < KS_STEPS; ++ks) {
    const int kg = ks * 4 + g;
    short8 b[4];
    #pragma unroll
    for (int j = 0; j < 4; ++j)
      if (j < ntw) b[j] = *(const short8*)(wk + (size_t)ks * (4 * NPAD * 8) + j * 128);
    // kg 25..27 (t>=200) rows are zero: value-mask A, keep MFMAs uniform.
    const bool av = (ks < 6) || (g == 0);
    short8 a[4];
    #pragma unroll
    for (int h = 0; h < 4; ++h)
      a[h] = av ? *(const short8*)&Xs[h * SLICE + (kg * 16 + l15) * 8]
                : (short8){0, 0, 0, 0, 0, 0, 0, 0};
    #pragma unroll
    for (int j = 0; j < 4; ++j)
      if (j < ntw) {
        #pragma unroll
        for (int h = 0; h < 4; ++h)
          acc[h][j] = __builtin_amdgcn_mfma_f32_16x16x32_bf16(a[h], b[j], acc[h][j], 0, 0, 0);
      }
  }

  // ---- fused epilogue (partial over this wave's s-range):
  // p = exp(tanh(z)), tanh bounded => no max pass.
  // C/D layout: col = l15 (= s within tile), row m = g*4 + r.
  float part[4][4], rs[4][4];
  #pragma unroll
  for (int h = 0; h < 4; ++h)
    #pragma unroll
    for (int r = 0; r < 4; ++r) { part[h][r] = 0.f; rs[h][r] = 0.f; }

  #pragma unroll
  for (int j = 0; j < 4; ++j) {
    if (j < ntw) {
      const int nt = nt0 + j;
      const int t  = nt * 16 + l15;
      const bool valid = (t < T_DIM);     // only fails for nt==12, l15>=8
      const int tc = valid ? t : (T_DIM - 1);
      const float bvn = bias[tc];
      const unsigned short* xp = &Xs[((tc >> 3) * 16) * 8 + (tc & 7)];
      #pragma unroll
      for (int r = 0; r < 4; ++r) {
        const int m = g * 4 + r;
        #pragma unroll
        for (int h = 0; h < 4; ++h) {
          float z  = acc[h][j][r] + bvn;
          float e  = __expf(2.0f * z);            // tanh = 1 - 2/(e^{2z}+1)
          float th = 1.0f - __fdividef(2.0f, e + 1.0f);
          float p  = valid ? __expf(th) : 0.0f;
          rs[h][r]   += p;
          part[h][r] += p * bf2f(xp[h * SLICE + m * 8]);  // X[t][dblk+h*16+m]
        }
      }
    }
  }
  // reduce over the 16 s-lanes
  #pragma unroll
  for (int off = 1; off <= 8; off <<= 1)
    #pragma unroll
    for (int h = 0; h < 4; ++h)
      #pragma unroll
      for (int r = 0; r < 4; ++r) {
        part[h][r] += __shfl_xor(part[h][r], off, 16);
        rs[h][r]   += __shfl_xor(rs[h][r],   off, 16);
      }

  // ---- cross-wave combine of s-partials
  if (l15 == 0) {
    #pragma unroll
    for (int h = 0; h < 4; ++h)
      #pragma unroll
      for (int r = 0; r < 4; ++r) {
        comb[wv][h * 16 + g * 4 + r][0] = part[h][r];
        comb[wv][h * 16 + g * 4 + r][1] = rs[h][r];
      }
  }
  __syncthreads();

  if (tid < 64) {
    float ps = 0.f, ss = 0.f;
    #pragma unroll
    for (int w = 0; w < 4; ++w) {
      ps += comb[w][tid][0];
      ss += comb[w][tid][1];
    }
    out[(size_t)bb * D_DIM + dblk + tid] = ps * __frcp_rn(ss);
  }
}

extern "C" void kernel_launch(void* const* d_in, const int* in_sizes, int n_in,
                              void* d_out, int out_size, void* d_ws, size_t ws_size,
                              hipStream_t stream) {
  const float* X  = (const float*)d_in[0];
  const float* W  = (const float*)d_in[1];
  const float* bs = (const float*)d_in[2];
  float* out = (float*)d_out;
  unsigned short* wf = (unsigned short*)d_ws;  // needs 224*208*2 = 93,184 B

  const int wtot = NKG * 8 * NPAD;
  hipLaunchKernelGGL(prep_w_kernel, dim3((wtot + 255) / 256), dim3(256), 0, stream,
                     W, wf);
  // 4096 blocks = 512 b * 8 d-tiles(64 cols); 4 s-split waves per block
  hipLaunchKernelGGL(attn_kernel, dim3(4096), dim3(256), 0, stream,
                     X, wf, bs, out);
}

// Round 8
// 315.277 us; speedup vs baseline: 1.0461x; 1.0078x over previous
//
#include <hip/hip_runtime.h>
#include <cstdint>
#include <cstddef>

#define B_DIM 512
#define T_DIM 200
#define D_DIM 512
#define NPAD  208   // N padded to 13*16
#define NKG   28    // K padded to 224 = 28 groups of 8
#define NT    13    // n-tiles of 16
#define KS_STEPS 7  // 224 / 32
// One 16-col X slice in LDS: [kg 0..24][m 0..15][j 0..7] bf16 = 3200 shorts
// + 8 pad shorts (bank stagger). FOUR slices per block (64 d-cols).
#define SLICE 3208

typedef short  short8  __attribute__((ext_vector_type(8)));
typedef float  floatx4 __attribute__((ext_vector_type(4)));

__device__ __forceinline__ unsigned short f2bf(float f) {
  unsigned int u = __float_as_uint(f);
  u += 0x7fffu + ((u >> 16) & 1u);   // round-to-nearest-even
  return (unsigned short)(u >> 16);
}
__device__ __forceinline__ float bf2f(unsigned short h) {
  return __uint_as_float(((unsigned int)h) << 16);
}
// packed f32x2 -> bf16x2 (RTNE)
__device__ __forceinline__ unsigned int cvt_pk_bf16(float a, float b) {
  unsigned int d;
  asm("v_cvt_pk_bf16_f32 %0, %1, %2" : "=v"(d) : "v"(a), "v"(b));
  return d;
}

// W (200x200 fp32) -> bf16, padded 224x208, B-fragment layout [k/8][n][k%8]
__global__ void prep_w_kernel(const float* __restrict__ W,
                              unsigned short* __restrict__ wf) {
  int idx = blockIdx.x * blockDim.x + threadIdx.x;
  if (idx >= NKG * 8 * NPAD) return;
  int k = idx / NPAD;
  int n = idx - k * NPAD;
  float v = (k < T_DIM && n < T_DIM) ? W[k * T_DIM + n] : 0.0f;
  wf[((size_t)(k >> 3) * NPAD + n) * 8 + (k & 7)] = f2bf(v);
}

// R7 post-mortem: wf-traffic halving AND K-loop dbuf AND occupancy 4->5 all
// measured ~neutral (R5/R6/R7 = 127/117/115 us). The common cost is VALU
// issue work (~6000 cyc/wave, half of it epilogue: 3 trans + ~9 full ops
// per score element) + 128 shuffles + staging addressing. R8 cuts issue
// work, keeping the R7 structure for clean attribution:
//  1) p' = exp(-2/(u+1)), u = exp(2(z+b)) -- softmax scale-invariance
//     (p' = p/e) removes bias-add, 2z-mul, and "1-" per element.
//  2) balanced s-split {3,3,3,3.5}: wave3 owns nt 9..12 (nt12 half-masked).
//  3) 2-round shuffle reduce + 8 KB LDS combine (was 4 rounds).
//  4) strength-reduced staging addressing (src/dst pointer marches).
__global__ __launch_bounds__(256, 4)
void attn_kernel(const float* __restrict__ X,
                 const unsigned short* __restrict__ wf,
                 const float* __restrict__ bias,
                 float* __restrict__ out) {
  __shared__ __align__(16) unsigned short Xs[4 * SLICE];
  __shared__ __align__(16) float comb[4][4][64][2];  // [wave][quad][d-col][p,rs]

  const int tid  = threadIdx.x;
  const int wv   = tid >> 6;
  const int lane = tid & 63;
  const int l15  = lane & 15;
  const int g    = lane >> 4;

  const int bid  = blockIdx.x;
  const int bb   = bid >> 3;              // batch item (8 blocks per item)
  const int dblk = (bid & 7) << 6;        // block's 64-col origin

  // ---- cooperative staging: 200 rows x 16 float4 (64 cols) = 3200 float4.
  // c4 and t&7 are it-invariant -> pure pointer marches per iteration.
  {
    const float* xb = X + (size_t)bb * (T_DIM * D_DIM) + dblk;
    const int c4 = tid & 15;              // float4 index within 64-col row
    const int t0 = tid >> 4;              // 0..15
    const float* src = xb + (size_t)t0 * D_DIM + (c4 << 2);
    unsigned short* dst = Xs + (c4 >> 2) * SLICE
                        + ((t0 >> 3) * 16 + ((c4 & 3) << 2)) * 8 + (t0 & 7);
    #pragma unroll
    for (int it = 0; it < 13; ++it) {
      if (it < 12 || tid < 128) {         // t = t0 + 16*it < 200
        float4 v = *(const float4*)src;
        unsigned int w01 = cvt_pk_bf16(v.x, v.y);
        unsigned int w23 = cvt_pk_bf16(v.z, v.w);
        dst[0]  = (unsigned short)(w01 & 0xffffu);
        dst[8]  = (unsigned short)(w01 >> 16);
        dst[16] = (unsigned short)(w23 & 0xffffu);
        dst[24] = (unsigned short)(w23 >> 16);
      }
      src += 16 * D_DIM;                  // t += 16
      dst += 256;                         // (t>>3) += 2 rows of [16][8]
    }
  }
  __syncthreads();

  // balanced s-split: wv0..2 -> 3 full tiles; wv3 -> nt 9..12 (12 is half)
  const int nt0 = 3 * wv;
  const int ntw = 3 + (wv == 3);

  floatx4 acc[4][4];                      // [h = d-slice][j = s-tile]
  #pragma unroll
  for (int h = 0; h < 4; ++h)
    #pragma unroll
    for (int j = 0; j < 4; ++j)
      acc[h][j] = (floatx4){0.f, 0.f, 0.f, 0.f};

  // per-lane base into wf for (kg = g, nt = nt0): frag j at +j*256 B,
  // ks step at +4*NPAD*8 shorts (compile-time multiples).
  const unsigned short* wk = wf + ((size_t)g * NPAD + nt0 * 16 + l15) * 8;

  // ---- K-loop: one B-frag feeds FOUR d-slices' MFMAs. Single-buffered.
  #pragma unroll
  for (int ks = 0; ks < KS_STEPS; ++ks) {
    const int kg = ks * 4 + g;
    short8 b[4];
    #pragma unroll
    for (int j = 0; j < 4; ++j)
      if (j < ntw) b[j] = *(const short8*)(wk + (size_t)ks * (4 * NPAD * 8) + j * 128);
    // kg 25..27 (t>=200) rows are zero: value-mask A, keep MFMAs uniform.
    const bool av = (ks < 6) || (g == 0);
    short8 a[4];
    #pragma unroll
    for (int h = 0; h < 4; ++h)
      a[h] = av ? *(const short8*)&Xs[h * SLICE + (kg * 16 + l15) * 8]
                : (short8){0, 0, 0, 0, 0, 0, 0, 0};
    #pragma unroll
    for (int j = 0; j < 4; ++j)
      if (j < ntw) {
        #pragma unroll
        for (int h = 0; h < 4; ++h)
          acc[h][j] = __builtin_amdgcn_mfma_f32_16x16x32_bf16(a[h], b[j], acc[h][j], 0, 0, 0);
      }
  }

  // ---- fused epilogue (partial over this wave's s-range):
  // softmax is scale-invariant: use p' = exp(tanh(z)-1) = exp(-2/(u+1)),
  // u = exp(2*(z+bias)) with bias pre-folded (bb2 = 2*bvn). No max pass
  // (tanh bounded). C/D layout: col = l15 (= s in tile), row m = g*4 + r.
  float part[4][4], rs[4][4];
  #pragma unroll
  for (int h = 0; h < 4; ++h)
    #pragma unroll
    for (int r = 0; r < 4; ++r) { part[h][r] = 0.f; rs[h][r] = 0.f; }

  #pragma unroll
  for (int j = 0; j < 4; ++j) {
    if (j < ntw) {
      const int nt = nt0 + j;
      const int t  = nt * 16 + l15;
      const bool valid = (t < T_DIM);     // only fails for nt==12, l15>=8
      const int tc = valid ? t : (T_DIM - 1);
      const float bb2 = 2.0f * bias[tc];
      const unsigned short* xp = &Xs[((tc >> 3) * 16) * 8 + (tc & 7)];
      #pragma unroll
      for (int r = 0; r < 4; ++r) {
        const int m = g * 4 + r;
        #pragma unroll
        for (int h = 0; h < 4; ++h) {
          float u  = __expf(__builtin_fmaf(acc[h][j][r], 2.0f, bb2));
          float v  = __fdividef(2.0f, u + 1.0f);
          float p0 = __expf(-v);          // = exp(tanh(z+b) - 1)
          float p  = valid ? p0 : 0.0f;
          rs[h][r]   += p;
          part[h][r] += p * bf2f(xp[h * SLICE + m * 8]);  // X[t][dblk+h*16+m]
        }
      }
    }
  }
  // 2-round reduce over s-lanes (groups of 4), finish in LDS
  #pragma unroll
  for (int off = 1; off <= 2; off <<= 1)
    #pragma unroll
    for (int h = 0; h < 4; ++h)
      #pragma unroll
      for (int r = 0; r < 4; ++r) {
        part[h][r] += __shfl_xor(part[h][r], off, 16);
        rs[h][r]   += __shfl_xor(rs[h][r],   off, 16);
      }

  if ((l15 & 3) == 0) {
    const int q = l15 >> 2;
    #pragma unroll
    for (int h = 0; h < 4; ++h)
      #pragma unroll
      for (int r = 0; r < 4; ++r) {
        const int idx = h * 16 + g * 4 + r;
        comb[wv][q][idx][0] = part[h][r];
        comb[wv][q][idx][1] = rs[h][r];
      }
  }
  __syncthreads();

  if (tid < 64) {
    float ps = 0.f, ss = 0.f;
    #pragma unroll
    for (int w = 0; w < 4; ++w)
      #pragma unroll
      for (int q = 0; q < 4; ++q) {
        const float2 v = *(const float2*)&comb[w][q][tid][0];
        ps += v.x;
        ss += v.y;
      }
    out[(size_t)bb * D_DIM + dblk + tid] = ps * __frcp_rn(ss);
  }
}

extern "C" void kernel_launch(void* const* d_in, const int* in_sizes, int n_in,
                              void* d_out, int out_size, void* d_ws, size_t ws_size,
                              hipStream_t stream) {
  const float* X  = (const float*)d_in[0];
  const float* W  = (const float*)d_in[1];
  const float* bs = (const float*)d_in[2];
  float* out = (float*)d_out;
  unsigned short* wf = (unsigned short*)d_ws;  // needs 224*208*2 = 93,184 B

  const int wtot = NKG * 8 * NPAD;
  hipLaunchKernelGGL(prep_w_kernel, dim3((wtot + 255) / 256), dim3(256), 0, stream,
                     W, wf);
  // 4096 blocks = 512 b * 8 d-tiles(64 cols); 4 s-split waves per block
  hipLaunchKernelGGL(attn_kernel, dim3(4096), dim3(256), 0, stream,
                     X, wf, bs, out);
}